// Round 1
// baseline (594.667 us; speedup 1.0000x reference)
//
#include <hip/hip_runtime.h>

#define NPIX (8 * 1024 * 1024)
#define IN 8
#define HID 16
#define OUTC 3
#define BLK 256
#define PPT 4   // pixels per thread

// Mask may be stored as 1-byte bools (numpy bool_) or widened int32 — detect at
// runtime. Random 0/1 bytes packed into u32 words give values > 1 almost surely;
// int32 storage gives only {0,1}. Reads 2 KB, safe under both layouts (>= 8 MB).
__global__ void detect_mask_kernel(const unsigned int* __restrict__ m,
                                   int* __restrict__ flag) {
    if (threadIdx.x == 0) {
        unsigned int acc = 0u;
        #pragma unroll 8
        for (int k = 0; k < 512; ++k) acc |= m[k];
        *flag = (acc > 1u) ? 1 : 0;   // 1 => byte-mask, 0 => int32-mask
    }
}

__global__ void __launch_bounds__(BLK) colormlp_kernel(
    const float* __restrict__ x,
    const void*  __restrict__ mask,
    const float* __restrict__ w0, const float* __restrict__ b0,
    const float* __restrict__ w1, const float* __restrict__ b1,
    const float* __restrict__ w2, const float* __restrict__ b2,
    float* __restrict__ out,
    const int* __restrict__ flag)
{
    // Weights transposed so each output-neuron row is contiguous -> ds_read_b128
    // broadcasts (all lanes same address, conflict-free).
    __shared__ __align__(16) float sW0[HID][IN];
    __shared__ __align__(16) float sW1[HID][HID];
    __shared__ __align__(16) float sW2[OUTC][HID];
    __shared__ float sB0[HID];
    __shared__ float sB1[HID];
    __shared__ float sB2[OUTC];

    const int t = threadIdx.x;
    if (t < HID * IN)   { int j = t >> 3, i = t & 7;  sW0[j][i] = w0[i * HID + j]; }
    {                     int j = t >> 4, i = t & 15; sW1[j][i] = w1[i * HID + j]; }
    if (t < OUTC * HID) { int j = t >> 4, i = t & 15; sW2[j][i] = w2[i * OUTC + j]; }
    if (t < HID)  { sB0[t] = b0[t]; sB1[t] = b1[t]; }
    if (t < OUTC) { sB2[t] = b2[t]; }
    __syncthreads();

    const int mflag = *flag;

    const unsigned int pix0 = (blockIdx.x * BLK + t) * PPT;

    // ---- load x: 4 consecutive pixels x 8 ch = 128 B contiguous per lane ----
    float xr[PPT][IN];
    {
        const float4* xp = (const float4*)(x + (size_t)pix0 * IN);
        #pragma unroll
        for (int p = 0; p < PPT; ++p) {
            float4 a = xp[2 * p];
            float4 b = xp[2 * p + 1];
            xr[p][0] = a.x; xr[p][1] = a.y; xr[p][2] = a.z; xr[p][3] = a.w;
            xr[p][4] = b.x; xr[p][5] = b.y; xr[p][6] = b.z; xr[p][7] = b.w;
        }
    }

    // ---- layer 0: h0 = relu(x @ w0 + b0) ----
    float h0[PPT][HID];
    #pragma unroll
    for (int j = 0; j < HID; ++j) {
        const float4 wa = ((const float4*)sW0[j])[0];
        const float4 wb = ((const float4*)sW0[j])[1];
        const float bj = sB0[j];
        #pragma unroll
        for (int p = 0; p < PPT; ++p) {
            float acc = bj;
            acc = fmaf(xr[p][0], wa.x, acc);
            acc = fmaf(xr[p][1], wa.y, acc);
            acc = fmaf(xr[p][2], wa.z, acc);
            acc = fmaf(xr[p][3], wa.w, acc);
            acc = fmaf(xr[p][4], wb.x, acc);
            acc = fmaf(xr[p][5], wb.y, acc);
            acc = fmaf(xr[p][6], wb.z, acc);
            acc = fmaf(xr[p][7], wb.w, acc);
            h0[p][j] = fmaxf(acc, 0.0f);
        }
    }

    // ---- layer 1: h1 = relu(h0 @ w1 + b1) ----
    float h1[PPT][HID];
    #pragma unroll
    for (int j = 0; j < HID; ++j) {
        const float4 wa = ((const float4*)sW1[j])[0];
        const float4 wb = ((const float4*)sW1[j])[1];
        const float4 wc = ((const float4*)sW1[j])[2];
        const float4 wd = ((const float4*)sW1[j])[3];
        const float bj = sB1[j];
        #pragma unroll
        for (int p = 0; p < PPT; ++p) {
            float acc = bj;
            acc = fmaf(h0[p][0],  wa.x, acc);
            acc = fmaf(h0[p][1],  wa.y, acc);
            acc = fmaf(h0[p][2],  wa.z, acc);
            acc = fmaf(h0[p][3],  wa.w, acc);
            acc = fmaf(h0[p][4],  wb.x, acc);
            acc = fmaf(h0[p][5],  wb.y, acc);
            acc = fmaf(h0[p][6],  wb.z, acc);
            acc = fmaf(h0[p][7],  wb.w, acc);
            acc = fmaf(h0[p][8],  wc.x, acc);
            acc = fmaf(h0[p][9],  wc.y, acc);
            acc = fmaf(h0[p][10], wc.z, acc);
            acc = fmaf(h0[p][11], wc.w, acc);
            acc = fmaf(h0[p][12], wd.x, acc);
            acc = fmaf(h0[p][13], wd.y, acc);
            acc = fmaf(h0[p][14], wd.z, acc);
            acc = fmaf(h0[p][15], wd.w, acc);
            h1[p][j] = fmaxf(acc, 0.0f);
        }
    }

    // ---- layer 2: y = sigmoid(h1 @ w2 + b2) ----
    float yv[PPT][OUTC];
    #pragma unroll
    for (int j = 0; j < OUTC; ++j) {
        const float4 wa = ((const float4*)sW2[j])[0];
        const float4 wb = ((const float4*)sW2[j])[1];
        const float4 wc = ((const float4*)sW2[j])[2];
        const float4 wd = ((const float4*)sW2[j])[3];
        const float bj = sB2[j];
        #pragma unroll
        for (int p = 0; p < PPT; ++p) {
            float acc = bj;
            acc = fmaf(h1[p][0],  wa.x, acc);
            acc = fmaf(h1[p][1],  wa.y, acc);
            acc = fmaf(h1[p][2],  wa.z, acc);
            acc = fmaf(h1[p][3],  wa.w, acc);
            acc = fmaf(h1[p][4],  wb.x, acc);
            acc = fmaf(h1[p][5],  wb.y, acc);
            acc = fmaf(h1[p][6],  wb.z, acc);
            acc = fmaf(h1[p][7],  wb.w, acc);
            acc = fmaf(h1[p][8],  wc.x, acc);
            acc = fmaf(h1[p][9],  wc.y, acc);
            acc = fmaf(h1[p][10], wc.z, acc);
            acc = fmaf(h1[p][11], wc.w, acc);
            acc = fmaf(h1[p][12], wd.x, acc);
            acc = fmaf(h1[p][13], wd.y, acc);
            acc = fmaf(h1[p][14], wd.z, acc);
            acc = fmaf(h1[p][15], wd.w, acc);
            float e = __expf(-acc);
            yv[p][j] = __builtin_amdgcn_rcpf(1.0f + e);
        }
    }

    // ---- mask load (uniform branch on detected layout) ----
    int mv[PPT];
    if (mflag) {
        uchar4 m4 = *(const uchar4*)((const unsigned char*)mask + pix0);
        mv[0] = m4.x; mv[1] = m4.y; mv[2] = m4.z; mv[3] = m4.w;
    } else {
        int4 m4 = *(const int4*)((const int*)mask + pix0);
        mv[0] = m4.x; mv[1] = m4.y; mv[2] = m4.z; mv[3] = m4.w;
    }

    // ---- blend + masked store: 48 B contiguous per lane ----
    float ov[PPT * OUTC];
    #pragma unroll
    for (int p = 0; p < PPT; ++p) {
        const float res = xr[p][3];
        #pragma unroll
        for (int c = 0; c < OUTC; ++c) {
            float rgb = xr[p][c];
            float bl = fmaf(res, yv[p][c] - rgb, rgb);  // (1-res)*rgb + res*y
            ov[p * OUTC + c] = mv[p] ? bl : 0.0f;
        }
    }
    float4* op = (float4*)(out + (size_t)pix0 * OUTC);
    op[0] = make_float4(ov[0], ov[1], ov[2],  ov[3]);
    op[1] = make_float4(ov[4], ov[5], ov[6],  ov[7]);
    op[2] = make_float4(ov[8], ov[9], ov[10], ov[11]);
}

extern "C" void kernel_launch(void* const* d_in, const int* in_sizes, int n_in,
                              void* d_out, int out_size, void* d_ws, size_t ws_size,
                              hipStream_t stream) {
    const float* x    = (const float*)d_in[0];
    const void*  mask = d_in[1];
    const float* w0   = (const float*)d_in[2];
    const float* b0   = (const float*)d_in[3];
    const float* w1   = (const float*)d_in[4];
    const float* b1   = (const float*)d_in[5];
    const float* w2   = (const float*)d_in[6];
    const float* b2   = (const float*)d_in[7];
    float* out = (float*)d_out;
    int* flag  = (int*)d_ws;

    detect_mask_kernel<<<1, 64, 0, stream>>>((const unsigned int*)mask, flag);

    const int grid = NPIX / (BLK * PPT);  // 8192
    colormlp_kernel<<<grid, BLK, 0, stream>>>(x, mask, w0, b0, w1, b1, w2, b2,
                                              out, flag);
}